// Round 8
// baseline (345.290 us; speedup 1.0000x reference)
//
#include <hip/hip_runtime.h>
#include <math.h>

// Problem constants (fixed by setup_inputs)
#define BB 32
#define NN 1024
#define DD 1024
#define HH 512

// out layout (floats): [one_hot 32*1024*1024][masked_acts 32*1024][kl 32][log_nom 32][log_norm 32]
#define OUT0_OFF 0
#define OUT1_OFF (BB * NN * NN)
#define OUT2_OFF (OUT1_OFF + BB * NN)
#define OUT3_OFF (OUT2_OFF + BB)
#define OUT4_OFF (OUT3_OFF + BB)

// ws layout (bytes): acts fp32 [32768] @0 ; Bfrag bf16 [1MB] @131072 ; rank int[32768] @1179648
#define WS_ACTS 0
#define WS_W1T  131072
#define WS_RANK 1179648

typedef __attribute__((ext_vector_type(8))) short short8;
typedef __attribute__((ext_vector_type(4))) float floatx4;
typedef __attribute__((ext_vector_type(4))) unsigned int uintx4;

// v_cvt_pk_bf16_f32: D[15:0]=bf16_rne(a), D[31:16]=bf16_rne(b).
// RNE == the f2bf bit-formula for all non-NaN inputs (q, W1 are finite).
__device__ inline unsigned int cvtpk(float a, float b) {
    unsigned int r;
    asm("v_cvt_pk_bf16_f32 %0, %1, %2" : "=v"(r) : "v"(a), "v"(b));
    return r;
}

// ---------------------------------------------------------------------------
// K0: W1 [d=1024][h=512] fp32 -> fragment-major bf16 Bfrag.
// Unit (s,tn) (s=K-step 0..31, tn=col-tile 0..31) holds the 64 lanes' MFMA
// B-fragments contiguously: lane l=(qd*16+c) gets 8 bf16 of
// W1T[n=tn*16+c][k=s*32+qd*8 .. +8]  (W1T[n][k] == W1[k][n]).
// So the GEMM's per-(s,tn) B load is ONE fully coalesced 1-KB wave read.
// ---------------------------------------------------------------------------
__global__ __launch_bounds__(64) void w1t_kernel(const float* __restrict__ W1,
                                                 unsigned short* __restrict__ Bfrag)
{
    const int s  = blockIdx.x;        // 0..31
    const int tn = blockIdx.y;        // 0..31
    const int l  = threadIdx.x;       // 0..63
    const int c  = l & 15, qd = l >> 4;
    const int n  = tn * 16 + c;
    float v[8];
    #pragma unroll
    for (int e = 0; e < 8; ++e)
        v[e] = W1[(size_t)(s * 32 + qd * 8 + e) * HH + n];
    uintx4 u;
    u.x = cvtpk(v[0], v[1]);
    u.y = cvtpk(v[2], v[3]);
    u.z = cvtpk(v[4], v[5]);
    u.w = cvtpk(v[6], v[7]);
    *(uintx4*)(Bfrag + ((size_t)(s * 32 + tn) * 64 + l) * 8) = u;
}

// ---------------------------------------------------------------------------
// K1: MFMA GEMM + fused relu/W2 epilogue.  ROUND-8: ZERO barriers, ZERO LDS.
// Rounds 0-7: seven schedule/geometry/staging variants all land 83-103 us with
// EVERY pipe ~10-16% busy -- no resource is the limiter; the invariant is the
// block-wide barrier between stage and consume (lockstep convoys; m233's
// 2-phase pathology).  This round removes synchronization entirely:
//  - B: fragment-major Bfrag (see K0) -> each (s,tn) B-frag is one coalesced
//    1-KB wave load from L2 (W1T 1 MB, L2-resident; zero cross-wave B reuse
//    in this layout, so traffic is unchanged vs LDS staging: 1 MB/block).
//  - A: per-lane direct from q: lane (c,qd) of tile tm reads exactly the 32 B
//    it feeds MFMA (q[m0+tm*16+c][s*32+qd*8..+8]), cvt via v_cvt_pk_bf16_f32
//    (RNE, bit-identical to prior f2bf).  4x wave redundancy (536 MB), served
//    by L2 (resident A-tiles ~2 MB/XCD < 4 MB).
//  - No __shared__ staging, no __syncthreads, no asm waitcnt, no setprio in
//    the loop: each wave free-runs load->MFMA; compiler schedules/pipelines
//    (its known-good regime, m97).  K ascending, same accumulation order as
//    rounds 0-4.  Geometry: 256 thr (4 waves), MT=64, wave w cols w*128,
//    acc[8][4]=128 AGPR -> 2 waves/SIMD.  LDS: 1 KB epilogue red only.
// Floors: MFMA 14 us, L2 ~1 GB -> ~30 us.  Tripwire: WRITE_SIZE >> 256 KB
// means spill -> geometry too fat.
// ---------------------------------------------------------------------------
#define MT 64

__global__ __launch_bounds__(256, 2) void gemm_acts_kernel(
    const float* __restrict__ q, const unsigned short* __restrict__ Bfrag,
    const float* __restrict__ b1, const float* __restrict__ W2,
    const float* __restrict__ b2, const float* __restrict__ unoise,
    float* __restrict__ acts_ws, float* __restrict__ out1)
{
    __shared__ float red[MT][4];

    const int tid  = threadIdx.x;
    const int w    = tid >> 6;         // wave 0..3
    const int lane = tid & 63;
    const int c    = lane & 15;
    const int qd   = lane >> 4;
    const int m0   = blockIdx.x * MT;

    floatx4 acc[8][4];
    #pragma unroll
    for (int tn = 0; tn < 8; ++tn)
        #pragma unroll
        for (int tm = 0; tm < 4; ++tm)
            acc[tn][tm] = (floatx4){0.f, 0.f, 0.f, 0.f};

    // A per-lane base pointers: row m0 + tm*16 + c, k offset qd*8
    const float* aptr[4];
    #pragma unroll
    for (int tm = 0; tm < 4; ++tm)
        aptr[tm] = q + (size_t)(m0 + tm * 16 + c) * DD + qd * 8;

    // B fragment units: (s*32 + w*8 + tn)*64 + lane, 8 shorts each
    const short8* bp = (const short8*)Bfrag;
    const int bbase = w * 8 * 64 + lane;   // + s*32*64 + tn*64 per access

    #pragma unroll 2
    for (int s = 0; s < 32; ++s) {
        short8 af[4];
        #pragma unroll
        for (int tm = 0; tm < 4; ++tm) {
            float4 v0 = *(const float4*)(aptr[tm] + s * 32);
            float4 v1 = *(const float4*)(aptr[tm] + s * 32 + 4);
            uintx4 u;
            u.x = cvtpk(v0.x, v0.y);
            u.y = cvtpk(v0.z, v0.w);
            u.z = cvtpk(v1.x, v1.y);
            u.w = cvtpk(v1.z, v1.w);
            af[tm] = __builtin_bit_cast(short8, u);
        }
        #pragma unroll
        for (int tn = 0; tn < 8; ++tn) {
            short8 bf = bp[(size_t)s * 32 * 64 + bbase + tn * 64];
            #pragma unroll
            for (int tm = 0; tm < 4; ++tm)
                acc[tn][tm] = __builtin_amdgcn_mfma_f32_16x16x32_bf16(
                    af[tm], bf, acc[tn][tm], 0, 0, 0);
        }
    }

    // epilogue: h = relu(acc + b1); rowsum += h*W2; reduce 16 cols + 4 waves
    float b1v[8], w2v[8];
    #pragma unroll
    for (int tn = 0; tn < 8; ++tn) {
        int col = w * 128 + tn * 16 + c;
        b1v[tn] = b1[col];
        w2v[tn] = W2[col];
    }
    #pragma unroll
    for (int tm = 0; tm < 4; ++tm) {
        #pragma unroll
        for (int r = 0; r < 4; ++r) {
            float p = 0.f;
            #pragma unroll
            for (int tn = 0; tn < 8; ++tn) {
                float v = acc[tn][tm][r] + b1v[tn];
                p = fmaf(fmaxf(v, 0.f), w2v[tn], p);
            }
            p += __shfl_xor(p, 1);
            p += __shfl_xor(p, 2);
            p += __shfl_xor(p, 4);
            p += __shfl_xor(p, 8);
            if (c == 0) red[tm * 16 + qd * 4 + r][w] = p;
        }
    }
    __syncthreads();
    if (tid < MT) {
        float raw = red[tid][0] + red[tid][1] + red[tid][2] + red[tid][3] + b2[0];
        float sp = fmaxf(raw, 0.f) + log1pf(expf(-fabsf(raw)));  // stable softplus
        int row = m0 + tid;
        float av = logf(fmaxf(sp, 1e-5f)) + unoise[row];
        acts_ws[row] = av;
        out1[row]    = av;
    }
}

// ---------------------------------------------------------------------------
// K2: zero the one-hot output region
// ---------------------------------------------------------------------------
__global__ __launch_bounds__(256) void zero_kernel(float4* __restrict__ p, int n4)
{
    int idx = blockIdx.x * blockDim.x + threadIdx.x;
    int stride = gridDim.x * blockDim.x;
    float4 z = make_float4(0.f, 0.f, 0.f, 0.f);
    for (int i = idx; i < n4; i += stride) p[i] = z;
}

// ---------------------------------------------------------------------------
// K3: rank-by-counting, spread across 128 blocks (4 per batch, 256 i each)
// ---------------------------------------------------------------------------
__global__ __launch_bounds__(256) void rank_kernel(
    const float* __restrict__ acts_ws, const float* __restrict__ gumbel,
    int* __restrict__ rank)
{
    __shared__ float P[NN];
    const int b = blockIdx.x >> 2;
    const int chunk = blockIdx.x & 3;
    const int tid = threadIdx.x;
    #pragma unroll
    for (int r = 0; r < 4; ++r) {
        int j = r * 256 + tid;
        P[j] = acts_ws[b * NN + j] + gumbel[b * NN + j];
    }
    __syncthreads();
    const int i = chunk * 256 + tid;
    const float pert = P[i];
    int cnt = 0;
    const float4* P4 = (const float4*)P;
    for (int j4 = 0; j4 < NN / 4; ++j4) {
        float4 pv = P4[j4];  // broadcast
        int j = j4 * 4;
        cnt += (pv.x > pert) || (pv.x == pert && j + 0 < i);
        cnt += (pv.y > pert) || (pv.y == pert && j + 1 < i);
        cnt += (pv.z > pert) || (pv.z == pert && j + 2 < i);
        cnt += (pv.w > pert) || (pv.w == pert && j + 3 < i);
    }
    rank[b * NN + i] = cnt;
}

// ---------------------------------------------------------------------------
// K4: per-batch permutation, one-hot scatter, PL likelihood, kl.
// Wave-level shfl suffix-scan + butterfly reductions: 4 block barriers total.
// ---------------------------------------------------------------------------
__global__ __launch_bounds__(1024) void permu_stats_kernel(
    const float* __restrict__ acts_ws, const int* __restrict__ rank,
    float* __restrict__ out0, float* __restrict__ out2,
    float* __restrict__ out3, float* __restrict__ out4)
{
    __shared__ float A[NN];
    __shared__ int   IDX[NN];
    __shared__ float WT[16];
    __shared__ float WSUF[17];
    __shared__ float P0[16], P1[16], P2[16];

    const int b = blockIdx.x;
    const int i = threadIdx.x;
    const int lane = i & 63;
    const int w = i >> 6;            // wave 0..15

    float a = acts_ws[b * NN + i];
    A[i] = a;
    IDX[rank[b * NN + i]] = i;
    __syncthreads();                                        // barrier A

    int perm = (i == 0) ? 0 : IDX[i - 1];
    out0[((size_t)b * NN + i) * NN + perm] = 1.0f;

    float e = expf(A[perm]);
    // intra-wave inclusive suffix sum of e
    float s = e;
    #pragma unroll
    for (int off = 1; off < 64; off <<= 1) {
        float v = __shfl_down(s, off);
        if (lane + off < 64) s += v;
    }
    if (lane == 0) WT[w] = s;        // wave total (suffix from lane 0)
    __syncthreads();                                        // barrier B
    if (w == 0) {
        float t = (lane < 16) ? WT[lane] : 0.f;
        #pragma unroll
        for (int off = 1; off < 16; off <<= 1) {
            float v = __shfl_down(t, off);
            if (lane + off < 16) t += v;
        }
        if (lane < 16) WSUF[lane] = t;   // sum over waves >= lane
        if (lane == 0) WSUF[16] = 0.f;
    }
    __syncthreads();                                        // barrier C

    float S = s + WSUF[w + 1];       // full suffix sum_{j>=i} e_j
    float term = logf(e + 1e-20f) - logf(S + 1e-20f);

    // three simultaneous full-wave butterfly reductions
    float r0 = term, r1 = a, r2 = expf(-fmaxf(a, -20.f));
    #pragma unroll
    for (int off = 1; off < 64; off <<= 1) {
        r0 += __shfl_xor(r0, off);
        r1 += __shfl_xor(r1, off);
        r2 += __shfl_xor(r2, off);
    }
    if (lane == 0) { P0[w] = r0; P1[w] = r1; P2[w] = r2; }
    __syncthreads();                                        // barrier D
    if (i == 0) {
        float t0 = 0.f, t1 = 0.f, t2 = 0.f;
        #pragma unroll
        for (int k = 0; k < 16; ++k) { t0 += P0[k]; t1 += P1[k]; t2 += P2[k]; }
        out3[b] = t0;
        out2[b] = -(float)NN + t1 + t2;
        out4[b] = 0.f;
    }
}

extern "C" void kernel_launch(void* const* d_in, const int* in_sizes, int n_in,
                              void* d_out, int out_size, void* d_ws, size_t ws_size,
                              hipStream_t stream)
{
    const float* q      = (const float*)d_in[0];
    const float* W1     = (const float*)d_in[2];
    const float* b1     = (const float*)d_in[3];
    const float* W2     = (const float*)d_in[4];
    const float* b2     = (const float*)d_in[5];
    const float* unoise = (const float*)d_in[6];
    const float* gumbel = (const float*)d_in[7];

    float* out  = (float*)d_out;
    char*  ws   = (char*)d_ws;
    float*          acts  = (float*)(ws + WS_ACTS);
    unsigned short* Bfrag = (unsigned short*)(ws + WS_W1T);
    int*            rank  = (int*)(ws + WS_RANK);

    w1t_kernel<<<dim3(32, 32), 64, 0, stream>>>(W1, Bfrag);
    gemm_acts_kernel<<<(BB * NN) / MT, 256, 0, stream>>>(q, Bfrag, b1, W2, b2,
                                                         unoise, acts,
                                                         out + OUT1_OFF);
    zero_kernel<<<8192, 256, 0, stream>>>((float4*)(out + OUT0_OFF),
                                          (BB * NN * NN) / 4);
    rank_kernel<<<BB * 4, 256, 0, stream>>>(acts, gumbel, rank);
    permu_stats_kernel<<<BB, 1024, 0, stream>>>(acts, rank,
                                                out + OUT0_OFF, out + OUT2_OFF,
                                                out + OUT3_OFF, out + OUT4_OFF);
}

// Round 9
// 309.476 us; speedup vs baseline: 1.1157x; 1.1157x over previous
//
#include <hip/hip_runtime.h>
#include <math.h>

// Problem constants (fixed by setup_inputs)
#define BB 32
#define NN 1024
#define DD 1024
#define HH 512

// out layout (floats): [one_hot 32*1024*1024][masked_acts 32*1024][kl 32][log_nom 32][log_norm 32]
#define OUT0_OFF 0
#define OUT1_OFF (BB * NN * NN)
#define OUT2_OFF (OUT1_OFF + BB * NN)
#define OUT3_OFF (OUT2_OFF + BB)
#define OUT4_OFF (OUT3_OFF + BB)

// ws layout (bytes): acts fp32 [32768] @0 ; W1T bf16 [512][1024] @131072 ; rank int[32768] @1179648
#define WS_ACTS 0
#define WS_W1T  131072
#define WS_RANK 1179648

typedef __attribute__((ext_vector_type(8))) short short8;
typedef __attribute__((ext_vector_type(4))) float floatx4;

__device__ inline unsigned int f2bf(float x) {  // RNE fp32 -> bf16 bits
    unsigned int u = __builtin_bit_cast(unsigned int, x);
    return (u + 0x7FFFu + ((u >> 16) & 1u)) >> 16;
}

// async global->LDS DMA, 16 B per lane, LDS dest = wave-uniform base + lane*16
__device__ inline void gload_lds16(const void* g, void* l) {
    __builtin_amdgcn_global_load_lds(
        (const __attribute__((address_space(1))) unsigned int*)g,
        (__attribute__((address_space(3))) unsigned int*)l, 16, 0, 0);
}

// ---------------------------------------------------------------------------
// K0: transpose + convert W1 [d=1024][h=512] fp32 -> W1T [h=512][d=1024] bf16
// ---------------------------------------------------------------------------
__global__ __launch_bounds__(1024) void w1t_kernel(const float* __restrict__ W1,
                                                   unsigned short* __restrict__ W1T)
{
    __shared__ float T[32][33];
    const int tx = threadIdx.x, ty = threadIdx.y;
    const int d0 = blockIdx.x * 32, h0 = blockIdx.y * 32;
    T[ty][tx] = W1[(d0 + ty) * HH + h0 + tx];
    __syncthreads();
    W1T[(size_t)(h0 + ty) * DD + d0 + tx] = (unsigned short)f2bf(T[tx][ty]);
}

// ---------------------------------------------------------------------------
// K1: MFMA GEMM + fused relu/W2 epilogue.  ROUND-9: BK=64, 16 periods.
// Cross-round evidence (R0-R8): per barrier-period cost is ~2.5 us FIXED,
// independent of staged bytes (R2: 72 KB/CU-step = 2.62 us; R3: 40 KB = 2.44)
// and of schedule variant; zero-sync direct-load (R8) pays raw per-load
// latency instead and is worse.  So: halve the period count.  R3's skeleton
// (best measured: rotated drain {vmcnt0+lgkm0; barrier; issue next; compute})
// kept verbatim; K-step doubled to 64.  At M=128 there is 1 block/CU, so the
// FULL 160 KB LDS is available: Bs 2x64K + As 2x16K = 163840 B exactly
// (epilogue red aliases the dead As[0]).  Total DMA/load instruction counts
// are IDENTICAL to R3 (8 B-DMA + 4 A-float4 per wave per period, 16 periods
// vs 4+2 over 32) -- clean test of the fixed-cost-per-period hypothesis.
// Swizzle (both-sides rule 21): stored byte b of any 128-B row holds element
// byte b ^ ((row&7)<<4).  Write side via pre-XOR'd source (A: float-group
// u^(row&7); B: DMA src unit u^(n&7)); read side: slot (ss*4+qd)^(row&7).
// For all frag reads row&7 == c&7 (wr, wc, tm*16, tn*16 are multiples of 8),
// so the XOR constant is a per-lane invariant.  K ascending -> bit-identical
// accumulation order vs all passing rounds.
// Geometry: 512 thr (8 waves, 2M x 4N), acc[8][4]=128 AGPR + ~110 VGPR < 256.
// Tripwires: WRITE_SIZE >> 256 KB = spill; launch failure = LDS cap.
// ---------------------------------------------------------------------------
#define MT 128
#define BK 64

__global__ __launch_bounds__(512, 2) void gemm_acts_kernel(
    const float* __restrict__ q, const unsigned short* __restrict__ W1T,
    const float* __restrict__ b1, const float* __restrict__ W2,
    const float* __restrict__ b2, const float* __restrict__ unoise,
    float* __restrict__ acts_ws, float* __restrict__ out1)
{
    __shared__ short As[2][MT * BK];   // 2 x 16384 B (128 rows x 128 B)
    __shared__ short Bs[2][HH * BK];   // 2 x 65536 B (512 rows x 128 B)

    const int tid  = threadIdx.x;
    const int w    = tid >> 6;         // wave 0..7
    const int lane = tid & 63;
    const int c    = lane & 15;
    const int qd   = lane >> 4;
    const int wr   = (w >> 2) * 64;    // wave row base
    const int wc   = (w & 3) * 128;    // wave col base
    const int m0   = blockIdx.x * MT;

    floatx4 acc[8][4];
    #pragma unroll
    for (int tn = 0; tn < 8; ++tn)
        #pragma unroll
        for (int tm = 0; tm < 4; ++tm)
            acc[tn][tm] = (floatx4){0.f, 0.f, 0.f, 0.f};

    // B DMA: wave w stages rows w*64..+64 (8 instrs x 8 rows).  Instr j,
    // lane l -> row n = w*64 + j*8 + (l>>3), unit u = l&7; LDS dst is linear
    // (base + l*16 == n*128 + u*16).  Source pre-XOR'd: unit u^(n&7), and
    // n&7 == l>>3.  Per-period k-offset: +kk*128 bytes into the 2048-B row.
    int boff[8];
    #pragma unroll
    for (int j = 0; j < 8; ++j) {
        int n = w * 64 + j * 8 + (lane >> 3);
        boff[j] = n * 2048 + (((lane & 7) ^ (lane >> 3)) << 4);
    }
    const char* w1tb = (const char*)W1T;

    // A staging: thread -> row arow = tid>>2 (0..127), two 16-B units
    // u0 = (tid&3)*2, u0+1.  Source float-groups u^(arow&7), 8 floats each.
    const int arow = tid >> 2;
    const int u0   = (tid & 3) * 2;
    const int s7   = arow & 7;
    const float* ap0 = q + (size_t)(m0 + arow) * DD + ((u0       ^ s7) * 8);
    const float* ap1 = q + (size_t)(m0 + arow) * DD + (((u0 + 1) ^ s7) * 8);
    const int adst = arow * 128 + u0 * 16;   // second store at +16

    // frag-read swizzle constants (row&7 == c&7 for every frag row)
    const int swz0 = ((qd)     ^ (c & 7)) << 4;   // sub-step 0 (K first 32)
    const int swz1 = ((4 + qd) ^ (c & 7)) << 4;   // sub-step 1 (K second 32)

    float4 a00, a01, a10, a11;

    // ---- prologue: pack A(0) -> As[0] (sync); DMA B(0) -> Bs[0]; load A(1) ----
    {
        float4 v00 = *(const float4*)(ap0);
        float4 v01 = *(const float4*)(ap0 + 4);
        float4 v10 = *(const float4*)(ap1);
        float4 v11 = *(const float4*)(ap1 + 4);
        uint4 p0, p1;
        p0.x = f2bf(v00.x) | (f2bf(v00.y) << 16);
        p0.y = f2bf(v00.z) | (f2bf(v00.w) << 16);
        p0.z = f2bf(v01.x) | (f2bf(v01.y) << 16);
        p0.w = f2bf(v01.z) | (f2bf(v01.w) << 16);
        p1.x = f2bf(v10.x) | (f2bf(v10.y) << 16);
        p1.y = f2bf(v10.z) | (f2bf(v10.w) << 16);
        p1.z = f2bf(v11.x) | (f2bf(v11.y) << 16);
        p1.w = f2bf(v11.z) | (f2bf(v11.w) << 16);
        *(uint4*)((char*)(&As[0][0]) + adst)      = p0;
        *(uint4*)((char*)(&As[0][0]) + adst + 16) = p1;
    }
    #pragma unroll
    for (int j = 0; j < 8; ++j)
        gload_lds16(w1tb + boff[j], (char*)(&Bs[0][0]) + w * 8192 + j * 1024);
    a00 = *(const float4*)(ap0 + BK);
    a01 = *(const float4*)(ap0 + BK + 4);
    a10 = *(const float4*)(ap1 + BK);
    a11 = *(const float4*)(ap1 + BK + 4);

    #pragma unroll 1
    for (int kk = 0; kk < 16; ++kk) {
        // rotated drain (R3): everything issued last period had a full period
        // in flight; one wait + one barrier per 64-K period.
        asm volatile("s_waitcnt vmcnt(0) lgkmcnt(0)" ::: "memory");
        __builtin_amdgcn_s_barrier();

        const int cur = kk & 1, nxt = cur ^ 1;
        if (kk < 15) {
            // B DMA(kk+1) -> Bs[nxt] (readers drained before the barrier)
            #pragma unroll
            for (int j = 0; j < 8; ++j)
                gload_lds16(w1tb + (boff[j] + (kk + 1) * 128),
                            (char*)(&Bs[nxt][0]) + w * 8192 + j * 1024);
            // pack A(kk+1) (regs drained by the vmcnt above) -> As[nxt]
            uint4 p0, p1;
            p0.x = f2bf(a00.x) | (f2bf(a00.y) << 16);
            p0.y = f2bf(a00.z) | (f2bf(a00.w) << 16);
            p0.z = f2bf(a01.x) | (f2bf(a01.y) << 16);
            p0.w = f2bf(a01.z) | (f2bf(a01.w) << 16);
            p1.x = f2bf(a10.x) | (f2bf(a10.y) << 16);
            p1.y = f2bf(a10.z) | (f2bf(a10.w) << 16);
            p1.z = f2bf(a11.x) | (f2bf(a11.y) << 16);
            p1.w = f2bf(a11.z) | (f2bf(a11.w) << 16);
            *(uint4*)((char*)(&As[nxt][0]) + adst)      = p0;
            *(uint4*)((char*)(&As[nxt][0]) + adst + 16) = p1;
            // issue A loads(kk+2)
            const int ka = (kk < 14) ? kk + 2 : 15;   // clamped dummy at s=14
            a00 = *(const float4*)(ap0 + ka * BK);
            a01 = *(const float4*)(ap0 + ka * BK + 4);
            a10 = *(const float4*)(ap1 + ka * BK);
            a11 = *(const float4*)(ap1 + ka * BK + 4);
        }

        const char* asC = (const char*)(&As[cur][0]);
        const char* bsC = (const char*)(&Bs[cur][0]);
        __builtin_amdgcn_s_setprio(1);
        // ---- sub-step 0: K [kk*64, kk*64+32) ----
        {
            short8 af[4];
            #pragma unroll
            for (int tm = 0; tm < 4; ++tm)
                af[tm] = *(const short8*)(asC + (wr + tm * 16 + c) * 128 + swz0);
            #pragma unroll
            for (int tn = 0; tn < 8; ++tn) {
                short8 bf = *(const short8*)(bsC + (wc + tn * 16 + c) * 128 + swz0);
                #pragma unroll
                for (int tm = 0; tm < 4; ++tm)
                    acc[tn][tm] = __builtin_amdgcn_mfma_f32_16x16x32_bf16(
                        af[tm], bf, acc[tn][tm], 0, 0, 0);
            }
        }
        // ---- sub-step 1: K [kk*64+32, kk*64+64) ----
        {
            short8 af[4];
            #pragma unroll
            for (int tm = 0; tm < 4; ++tm)
                af[tm] = *(const short8*)(asC + (wr + tm * 16 + c) * 128 + swz1);
            #pragma unroll
            for (int tn = 0; tn < 8; ++tn) {
                short8 bf = *(const short8*)(bsC + (wc + tn * 16 + c) * 128 + swz1);
                #pragma unroll
                for (int tm = 0; tm < 4; ++tm)
                    acc[tn][tm] = __builtin_amdgcn_mfma_f32_16x16x32_bf16(
                        af[tm], bf, acc[tn][tm], 0, 0, 0);
            }
        }
        __builtin_amdgcn_s_setprio(0);
    }

    // epilogue: h = relu(acc + b1); rowsum += h*W2; reduce 16 cols + 4 N-waves.
    // red aliases As[0] (dead: last read at kk=14, drained before barrier 15).
    float (*red)[4] = (float (*)[4])(&As[0][0]);
    float b1v[8], w2v[8];
    #pragma unroll
    for (int tn = 0; tn < 8; ++tn) {
        int col = wc + tn * 16 + c;
        b1v[tn] = b1[col];
        w2v[tn] = W2[col];
    }
    #pragma unroll
    for (int tm = 0; tm < 4; ++tm) {
        #pragma unroll
        for (int r = 0; r < 4; ++r) {
            float p = 0.f;
            #pragma unroll
            for (int tn = 0; tn < 8; ++tn) {
                float v = acc[tn][tm][r] + b1v[tn];
                p = fmaf(fmaxf(v, 0.f), w2v[tn], p);
            }
            p += __shfl_xor(p, 1);
            p += __shfl_xor(p, 2);
            p += __shfl_xor(p, 4);
            p += __shfl_xor(p, 8);
            if (c == 0) red[wr + tm * 16 + qd * 4 + r][w & 3] = p;
        }
    }
    __syncthreads();
    if (tid < MT) {
        float raw = red[tid][0] + red[tid][1] + red[tid][2] + red[tid][3] + b2[0];
        float sp = fmaxf(raw, 0.f) + log1pf(expf(-fabsf(raw)));  // stable softplus
        int row = m0 + tid;
        float av = logf(fmaxf(sp, 1e-5f)) + unoise[row];
        acts_ws[row] = av;
        out1[row]    = av;
    }
}

// ---------------------------------------------------------------------------
// K2: zero the one-hot output region
// ---------------------------------------------------------------------------
__global__ __launch_bounds__(256) void zero_kernel(float4* __restrict__ p, int n4)
{
    int idx = blockIdx.x * blockDim.x + threadIdx.x;
    int stride = gridDim.x * blockDim.x;
    float4 z = make_float4(0.f, 0.f, 0.f, 0.f);
    for (int i = idx; i < n4; i += stride) p[i] = z;
}

// ---------------------------------------------------------------------------
// K3: rank-by-counting, spread across 128 blocks (4 per batch, 256 i each)
// ---------------------------------------------------------------------------
__global__ __launch_bounds__(256) void rank_kernel(
    const float* __restrict__ acts_ws, const float* __restrict__ gumbel,
    int* __restrict__ rank)
{
    __shared__ float P[NN];
    const int b = blockIdx.x >> 2;
    const int chunk = blockIdx.x & 3;
    const int tid = threadIdx.x;
    #pragma unroll
    for (int r = 0; r < 4; ++r) {
        int j = r * 256 + tid;
        P[j] = acts_ws[b * NN + j] + gumbel[b * NN + j];
    }
    __syncthreads();
    const int i = chunk * 256 + tid;
    const float pert = P[i];
    int cnt = 0;
    const float4* P4 = (const float4*)P;
    for (int j4 = 0; j4 < NN / 4; ++j4) {
        float4 pv = P4[j4];  // broadcast
        int j = j4 * 4;
        cnt += (pv.x > pert) || (pv.x == pert && j + 0 < i);
        cnt += (pv.y > pert) || (pv.y == pert && j + 1 < i);
        cnt += (pv.z > pert) || (pv.z == pert && j + 2 < i);
        cnt += (pv.w > pert) || (pv.w == pert && j + 3 < i);
    }
    rank[b * NN + i] = cnt;
}

// ---------------------------------------------------------------------------
// K4: per-batch permutation, one-hot scatter, PL likelihood, kl.
// Wave-level shfl suffix-scan + butterfly reductions: 4 block barriers total.
// ---------------------------------------------------------------------------
__global__ __launch_bounds__(1024) void permu_stats_kernel(
    const float* __restrict__ acts_ws, const int* __restrict__ rank,
    float* __restrict__ out0, float* __restrict__ out2,
    float* __restrict__ out3, float* __restrict__ out4)
{
    __shared__ float A[NN];
    __shared__ int   IDX[NN];
    __shared__ float WT[16];
    __shared__ float WSUF[17];
    __shared__ float P0[16], P1[16], P2[16];

    const int b = blockIdx.x;
    const int i = threadIdx.x;
    const int lane = i & 63;
    const int w = i >> 6;            // wave 0..15

    float a = acts_ws[b * NN + i];
    A[i] = a;
    IDX[rank[b * NN + i]] = i;
    __syncthreads();                                        // barrier A

    int perm = (i == 0) ? 0 : IDX[i - 1];
    out0[((size_t)b * NN + i) * NN + perm] = 1.0f;

    float e = expf(A[perm]);
    // intra-wave inclusive suffix sum of e
    float s = e;
    #pragma unroll
    for (int off = 1; off < 64; off <<= 1) {
        float v = __shfl_down(s, off);
        if (lane + off < 64) s += v;
    }
    if (lane == 0) WT[w] = s;        // wave total (suffix from lane 0)
    __syncthreads();                                        // barrier B
    if (w == 0) {
        float t = (lane < 16) ? WT[lane] : 0.f;
        #pragma unroll
        for (int off = 1; off < 16; off <<= 1) {
            float v = __shfl_down(t, off);
            if (lane + off < 16) t += v;
        }
        if (lane < 16) WSUF[lane] = t;   // sum over waves >= lane
        if (lane == 0) WSUF[16] = 0.f;
    }
    __syncthreads();                                        // barrier C

    float S = s + WSUF[w + 1];       // full suffix sum_{j>=i} e_j
    float term = logf(e + 1e-20f) - logf(S + 1e-20f);

    // three simultaneous full-wave butterfly reductions
    float r0 = term, r1 = a, r2 = expf(-fmaxf(a, -20.f));
    #pragma unroll
    for (int off = 1; off < 64; off <<= 1) {
        r0 += __shfl_xor(r0, off);
        r1 += __shfl_xor(r1, off);
        r2 += __shfl_xor(r2, off);
    }
    if (lane == 0) { P0[w] = r0; P1[w] = r1; P2[w] = r2; }
    __syncthreads();                                        // barrier D
    if (i == 0) {
        float t0 = 0.f, t1 = 0.f, t2 = 0.f;
        #pragma unroll
        for (int k = 0; k < 16; ++k) { t0 += P0[k]; t1 += P1[k]; t2 += P2[k]; }
        out3[b] = t0;
        out2[b] = -(float)NN + t1 + t2;
        out4[b] = 0.f;
    }
}

extern "C" void kernel_launch(void* const* d_in, const int* in_sizes, int n_in,
                              void* d_out, int out_size, void* d_ws, size_t ws_size,
                              hipStream_t stream)
{
    const float* q      = (const float*)d_in[0];
    const float* W1     = (const float*)d_in[2];
    const float* b1     = (const float*)d_in[3];
    const float* W2     = (const float*)d_in[4];
    const float* b2     = (const float*)d_in[5];
    const float* unoise = (const float*)d_in[6];
    const float* gumbel = (const float*)d_in[7];

    float* out  = (float*)d_out;
    char*  ws   = (char*)d_ws;
    float*          acts = (float*)(ws + WS_ACTS);
    unsigned short* W1T  = (unsigned short*)(ws + WS_W1T);
    int*            rank = (int*)(ws + WS_RANK);

    w1t_kernel<<<dim3(32, 16), dim3(32, 32), 0, stream>>>(W1, W1T);
    gemm_acts_kernel<<<(BB * NN) / MT, 512, 0, stream>>>(q, W1T, b1, W2, b2,
                                                         unoise, acts,
                                                         out + OUT1_OFF);
    zero_kernel<<<8192, 256, 0, stream>>>((float4*)(out + OUT0_OFF),
                                          (BB * NN * NN) / 4);
    rank_kernel<<<BB * 4, 256, 0, stream>>>(acts, gumbel, rank);
    permu_stats_kernel<<<BB, 1024, 0, stream>>>(acts, rank,
                                                out + OUT0_OFF, out + OUT2_OFF,
                                                out + OUT3_OFF, out + OUT4_OFF);
}